// Round 1
// baseline (443.659 us; speedup 1.0000x reference)
//
#include <hip/hip_runtime.h>
#include <hip/hip_bf16.h>
#include <math.h>

// Problem constants (fixed by the reference)
constexpr int Bc = 4;
constexpr int Nc = 2048;
constexpr int Fc = 64;    // F == F_
constexpr int Hc = 4;
constexpr int IDX_CAP = 1024;  // nnz/row ~21.5 (binom(2048,0.01)+1); 1024 is absurdly safe

__device__ __forceinline__ float readlane_f(float v, int l) {
    return __int_as_float(__builtin_amdgcn_readlane(__float_as_int(v), l));
}

// ---------------------------------------------------------------------------
// Kernel 1: per-head projections + attention logit scalars.
//   feat_self[b,h,n,e] = sum_f X[b,n,f] * W_self[h,f,e]   (same for neigh)
//   s_self[b,h,n]      = sum_e feat_self[b,h,n,e] * a_self[h,e]
// Strategy: one block per (b, h, 64-node tile). Each lane owns column e of
// W_self[h] and W_neigh[h] in REGISTERS (64+64 VGPRs) — loaded once, reused
// for 16 nodes per wave. X row element f broadcast via v_readlane (SGPR
// operand to the FMA). No LDS in the inner loop.
// ---------------------------------------------------------------------------
__global__ __launch_bounds__(256) void proj_kernel(
    const float* __restrict__ X,
    const float* __restrict__ Wself, const float* __restrict__ Wneigh,
    const float* __restrict__ aSelf, const float* __restrict__ aNeigh,
    float* __restrict__ fS, float* __restrict__ fN,
    float* __restrict__ sS, float* __restrict__ sN)
{
    const int lane = threadIdx.x & 63;
    const int wave = threadIdx.x >> 6;
    const int ntiles = Nc / 64;
    const int tile = blockIdx.x % ntiles;
    const int bh   = blockIdx.x / ntiles;
    const int h = bh % Hc;
    const int b = bh / Hc;

    // W columns into registers: wSr[f] = Wself[h][f][lane]
    float wSr[64], wNr[64];
    const float* wsb = Wself  + (size_t)h * Fc * Fc + lane;
    const float* wnb = Wneigh + (size_t)h * Fc * Fc + lane;
#pragma unroll
    for (int f = 0; f < 64; ++f) {
        wSr[f] = wsb[f * 64];
        wNr[f] = wnb[f * 64];
    }
    const float aSe = aSelf[h * Fc + lane];
    const float aNe = aNeigh[h * Fc + lane];

    for (int ni = 0; ni < 16; ++ni) {
        const int n = tile * 64 + wave * 16 + ni;
        const float x = X[((size_t)b * Nc + n) * Fc + lane];
        float accS = 0.f, accN = 0.f;
#pragma unroll
        for (int f = 0; f < 64; ++f) {
            const float xf = readlane_f(x, f);   // SGPR broadcast of X[b,n,f]
            accS = fmaf(xf, wSr[f], accS);
            accN = fmaf(xf, wNr[f], accN);
        }
        const size_t row = (size_t)(b * Hc + h) * Nc + n;
        fS[row * Fc + lane] = accS;
        fN[row * Fc + lane] = accN;

        float rs = accS * aSe, rn = accN * aNe;
#pragma unroll
        for (int o = 32; o > 0; o >>= 1) {
            rs += __shfl_xor(rs, o, 64);
            rn += __shfl_xor(rn, o, 64);
        }
        if (lane == 0) { sS[row] = rs; sN[row] = rn; }
    }
}

// ---------------------------------------------------------------------------
// Kernel 2: fused attention + normalization + sparse aggregation + relu out.
// One block per (b, i):
//   phase 1: stream A[b,i,:] (float4), for each nonzero j compute the 4
//            head sigmoids into LDS, accumulate row sums, compact j-list.
//   phase 2: write att[b, h, i, :] = lds * inv  (coalesced float4 stores)
//   phase 3: node_feat = (feat_self + sum_j sig_j * feat_neigh[j]) * inv,
//            relu, write out[b, i, h*64+e].
// Masked entries are exactly 0 (sigmoid(-1e16) == 0 in fp32) — no exp needed.
// ---------------------------------------------------------------------------
__global__ __launch_bounds__(256) void att_kernel(
    const float* __restrict__ A,
    const float* __restrict__ sS, const float* __restrict__ sN,
    const float* __restrict__ fS, const float* __restrict__ fN,
    float* __restrict__ out, float* __restrict__ att)
{
    __shared__ __align__(16) float att_s[Hc * Nc];   // 32 KB
    __shared__ int   idx_s[IDX_CAP];                 // 4 KB
    __shared__ float sum_s[Hc];
    __shared__ int   cnt_s;

    const int t = threadIdx.x;
    const int b = blockIdx.x / Nc;
    const int i = blockIdx.x % Nc;

    if (t < Hc) sum_s[t] = 0.f;
    if (t == 0) cnt_s = 0;
    float4* as4 = (float4*)att_s;
#pragma unroll
    for (int k = 0; k < (Hc * Nc / 4) / 256; ++k)   // 8 iters: zero 32 KB
        as4[k * 256 + t] = float4{0.f, 0.f, 0.f, 0.f};
    __syncthreads();

    float ss[Hc];
#pragma unroll
    for (int h = 0; h < Hc; ++h) ss[h] = sS[((size_t)b * Hc + h) * Nc + i];

    const float4* Arow4 = (const float4*)(A + ((size_t)b * Nc + i) * Nc);
#pragma unroll
    for (int rep = 0; rep < Nc / (256 * 4); ++rep) {   // 2 iters
        const int v = rep * 256 + t;
        const float4 a4 = Arow4[v];
        const float av[4] = {a4.x, a4.y, a4.z, a4.w};
#pragma unroll
        for (int c = 0; c < 4; ++c) {
            if (av[c] != 0.f) {
                const int j = v * 4 + c;
                const int slot = atomicAdd(&cnt_s, 1);
                if (slot < IDX_CAP) idx_s[slot] = j;
#pragma unroll
                for (int h = 0; h < Hc; ++h) {
                    float z = ss[h] + sN[((size_t)b * Hc + h) * Nc + j];
                    z = z > 0.f ? z : 0.2f * z;          // leaky_relu(0.2)
                    const float sig = 1.f / (1.f + expf(-z));
                    att_s[h * Nc + j] = sig;
                    atomicAdd(&sum_s[h], sig);
                }
            }
        }
    }
    __syncthreads();

    // phase 2: normalized att rows, coalesced float4
#pragma unroll
    for (int h = 0; h < Hc; ++h) {
        const float invh = 1.f / (1.f + sum_s[h]);
        float4* dst = (float4*)(att + (((size_t)b * Hc + h) * Nc + i) * (size_t)Nc);
#pragma unroll
        for (int k = 0; k < (Nc / 4) / 256; ++k) {   // 2 iters
            float4 vv = as4[h * (Nc / 4) + k * 256 + t];
            vv.x *= invh; vv.y *= invh; vv.z *= invh; vv.w *= invh;
            dst[k * 256 + t] = vv;
        }
    }

    // phase 3: sparse aggregation + relu
    {
        const int h = t >> 6, e = t & 63;
        const float invh = 1.f / (1.f + sum_s[h]);
        const size_t plane = (size_t)(b * Hc + h) * Nc;
        float acc = fS[(plane + i) * Fc + e];
        const int cnt = min(cnt_s, IDX_CAP);
        for (int k = 0; k < cnt; ++k) {
            const int j = idx_s[k];                    // LDS broadcast
            const float w = att_s[h * Nc + j];         // LDS broadcast
            acc = fmaf(w, fN[(plane + j) * Fc + e], acc);  // 256B coalesced gather
        }
        acc *= invh;
        acc = acc > 0.f ? acc : 0.f;
        out[((size_t)b * Nc + i) * (Hc * Fc) + t] = acc;
    }
}

extern "C" void kernel_launch(void* const* d_in, const int* in_sizes, int n_in,
                              void* d_out, int out_size, void* d_ws, size_t ws_size,
                              hipStream_t stream) {
    const float* X      = (const float*)d_in[0];
    const float* A      = (const float*)d_in[1];
    const float* Wself  = (const float*)d_in[2];
    const float* Wneigh = (const float*)d_in[3];
    const float* aSelf  = (const float*)d_in[4];
    const float* aNeigh = (const float*)d_in[5];

    float* out = (float*)d_out;                       // [B, N, H*F] = 2,097,152
    float* att = out + (size_t)Bc * Nc * Hc * Fc;     // [B, H, N, N] = 67,108,864

    float* ws = (float*)d_ws;                         // needs ~17 MB
    float* fS = ws;                                   // [B,H,N,F]
    float* fN = fS + (size_t)Bc * Hc * Nc * Fc;       // [B,H,N,F]
    float* sS = fN + (size_t)Bc * Hc * Nc * Fc;       // [B,H,N]
    float* sN = sS + (size_t)Bc * Hc * Nc;            // [B,H,N]

    proj_kernel<<<Bc * Hc * (Nc / 64), 256, 0, stream>>>(
        X, Wself, Wneigh, aSelf, aNeigh, fS, fN, sS, sN);
    att_kernel<<<Bc * Nc, 256, 0, stream>>>(
        A, sS, sN, fS, fN, out, att);
}

// Round 3
// 393.159 us; speedup vs baseline: 1.1284x; 1.1284x over previous
//
#include <hip/hip_runtime.h>
#include <hip/hip_bf16.h>
#include <math.h>

// Problem constants (fixed by the reference)
constexpr int Bc = 4;
constexpr int Nc = 2048;
constexpr int Fc = 64;    // F == F_
constexpr int Hc = 4;
constexpr int IDX_CAP = 256;  // nnz/row: mean ~21.5, 6-sigma max ~48. 256 is safe.

typedef float f32x4 __attribute__((ext_vector_type(4)));  // native vector for nontemporal builtins

__device__ __forceinline__ float readlane_f(float v, int l) {
    return __int_as_float(__builtin_amdgcn_readlane(__float_as_int(v), l));
}

// ---------------------------------------------------------------------------
// Kernel 1: per-head projections + attention logit scalars.
//   feat_self[b,h,n,e] = sum_f X[b,n,f] * W_self[h,f,e]   (same for neigh)
//   s_self[b,h,n]      = sum_e feat_self[b,h,n,e] * a_self[h,e]
// One block per (b, h, 64-node tile). Each lane owns column e of W_self[h]
// and W_neigh[h] in REGISTERS; X row elements broadcast via v_readlane.
// ---------------------------------------------------------------------------
__global__ __launch_bounds__(256) void proj_kernel(
    const float* __restrict__ X,
    const float* __restrict__ Wself, const float* __restrict__ Wneigh,
    const float* __restrict__ aSelf, const float* __restrict__ aNeigh,
    float* __restrict__ fS, float* __restrict__ fN,
    float* __restrict__ sS, float* __restrict__ sN)
{
    const int lane = threadIdx.x & 63;
    const int wave = threadIdx.x >> 6;
    const int ntiles = Nc / 64;
    const int tile = blockIdx.x % ntiles;
    const int bh   = blockIdx.x / ntiles;
    const int h = bh % Hc;
    const int b = bh / Hc;

    float wSr[64], wNr[64];
    const float* wsb = Wself  + (size_t)h * Fc * Fc + lane;
    const float* wnb = Wneigh + (size_t)h * Fc * Fc + lane;
#pragma unroll
    for (int f = 0; f < 64; ++f) {
        wSr[f] = wsb[f * 64];
        wNr[f] = wnb[f * 64];
    }
    const float aSe = aSelf[h * Fc + lane];
    const float aNe = aNeigh[h * Fc + lane];

    for (int ni = 0; ni < 16; ++ni) {
        const int n = tile * 64 + wave * 16 + ni;
        const float x = X[((size_t)b * Nc + n) * Fc + lane];
        float accS = 0.f, accN = 0.f;
#pragma unroll
        for (int f = 0; f < 64; ++f) {
            const float xf = readlane_f(x, f);
            accS = fmaf(xf, wSr[f], accS);
            accN = fmaf(xf, wNr[f], accN);
        }
        const size_t row = (size_t)(b * Hc + h) * Nc + n;
        fS[row * Fc + lane] = accS;
        fN[row * Fc + lane] = accN;

        float rs = accS * aSe, rn = accN * aNe;
#pragma unroll
        for (int o = 32; o > 0; o >>= 1) {
            rs += __shfl_xor(rs, o, 64);
            rn += __shfl_xor(rn, o, 64);
        }
        if (lane == 0) { sS[row] = rs; sN[row] = rn; }
    }
}

// ---------------------------------------------------------------------------
// Kernel 2: fused attention + normalization + sparse aggregation + relu out.
// One block per (b, i). Sigmoids live in REGISTERS (thread t owns columns
// {rep*1024 + t*4 + c}); row sums via register accumulators + tree reduce;
// a compact (j, sig[4]) list in ~5 KB LDS feeds the sparse aggregation.
// Masked entries are exactly 0 in fp32 (sigmoid(-1e16)==0) — no exp needed.
// A read and att write are nontemporal (read/write-once streams), keeping
// L2/L3 for the fN gathers.
// ---------------------------------------------------------------------------
__global__ __launch_bounds__(256) void att_kernel(
    const float* __restrict__ A,
    const float* __restrict__ sS, const float* __restrict__ sN,
    const float* __restrict__ fS, const float* __restrict__ fN,
    float* __restrict__ out, float* __restrict__ att)
{
    __shared__ int   idx_s[IDX_CAP];
    __shared__ float sig_s[IDX_CAP * Hc];
    __shared__ float wsum_s[4][Hc];
    __shared__ int   cnt_s;

    const int t = threadIdx.x;
    const int lane = t & 63;
    const int wave = t >> 6;
    const int b = blockIdx.x / Nc;
    const int i = blockIdx.x % Nc;

    if (t == 0) cnt_s = 0;
    __syncthreads();

    float ss[Hc];
#pragma unroll
    for (int h = 0; h < Hc; ++h) ss[h] = sS[((size_t)b * Hc + h) * Nc + i];

    float sigv[2][4][Hc];   // [rep][c][h] — this thread's 8 columns × 4 heads
#pragma unroll
    for (int r = 0; r < 2; ++r)
#pragma unroll
        for (int c = 0; c < 4; ++c)
#pragma unroll
            for (int h = 0; h < Hc; ++h) sigv[r][c][h] = 0.f;
    float sumh[Hc] = {0.f, 0.f, 0.f, 0.f};

    const f32x4* Arow4 = (const f32x4*)(A + ((size_t)b * Nc + i) * Nc);
#pragma unroll
    for (int rep = 0; rep < 2; ++rep) {
        const int v = rep * 256 + t;
        const f32x4 a4 = __builtin_nontemporal_load(&Arow4[v]);
        const float av[4] = {a4.x, a4.y, a4.z, a4.w};
#pragma unroll
        for (int c = 0; c < 4; ++c) {
            if (av[c] != 0.f) {
                const int j = v * 4 + c;
                const int slot = atomicAdd(&cnt_s, 1);
                if (slot < IDX_CAP) idx_s[slot] = j;
#pragma unroll
                for (int h = 0; h < Hc; ++h) {
                    float z = ss[h] + sN[((size_t)b * Hc + h) * Nc + j];
                    z = z > 0.f ? z : 0.2f * z;            // leaky_relu(0.2)
                    const float sig = 1.f / (1.f + __expf(-z));
                    sigv[rep][c][h] = sig;
                    sumh[h] += sig;
                    if (slot < IDX_CAP) sig_s[slot * Hc + h] = sig;
                }
            }
        }
    }

    // block reduction of per-head sums: wave shuffle tree + LDS across waves
#pragma unroll
    for (int o = 32; o > 0; o >>= 1)
#pragma unroll
        for (int h = 0; h < Hc; ++h) sumh[h] += __shfl_xor(sumh[h], o, 64);
    if (lane == 0)
#pragma unroll
        for (int h = 0; h < Hc; ++h) wsum_s[wave][h] = sumh[h];
    __syncthreads();   // also publishes idx_s / sig_s / cnt_s

    float inv[Hc];
#pragma unroll
    for (int h = 0; h < Hc; ++h)
        inv[h] = 1.f / (1.f + wsum_s[0][h] + wsum_s[1][h] + wsum_s[2][h] + wsum_s[3][h]);

    // phase 2: normalized att rows straight from registers (nontemporal)
#pragma unroll
    for (int h = 0; h < Hc; ++h) {
        f32x4* dst = (f32x4*)(att + (((size_t)b * Hc + h) * Nc + i) * (size_t)Nc);
#pragma unroll
        for (int rep = 0; rep < 2; ++rep) {
            const int v = rep * 256 + t;
            f32x4 vv;
            vv.x = sigv[rep][0][h] * inv[h];
            vv.y = sigv[rep][1][h] * inv[h];
            vv.z = sigv[rep][2][h] * inv[h];
            vv.w = sigv[rep][3][h] * inv[h];
            __builtin_nontemporal_store(vv, &dst[v]);
        }
    }

    // phase 3: sparse aggregation + relu
    {
        const int h = t >> 6, e = t & 63;
        const float invh = inv[h];
        const size_t plane = (size_t)(b * Hc + h) * Nc;
        float acc = fS[(plane + i) * Fc + e];
        const int cnt = min(cnt_s, IDX_CAP);
        for (int k = 0; k < cnt; ++k) {
            const int j = idx_s[k];                    // LDS broadcast
            const float w = sig_s[k * Hc + h];         // LDS broadcast
            acc = fmaf(w, fN[(plane + j) * Fc + e], acc);  // 256B coalesced gather
        }
        acc *= invh;
        acc = acc > 0.f ? acc : 0.f;
        out[((size_t)b * Nc + i) * (Hc * Fc) + t] = acc;
    }
}

extern "C" void kernel_launch(void* const* d_in, const int* in_sizes, int n_in,
                              void* d_out, int out_size, void* d_ws, size_t ws_size,
                              hipStream_t stream) {
    const float* X      = (const float*)d_in[0];
    const float* A      = (const float*)d_in[1];
    const float* Wself  = (const float*)d_in[2];
    const float* Wneigh = (const float*)d_in[3];
    const float* aSelf  = (const float*)d_in[4];
    const float* aNeigh = (const float*)d_in[5];

    float* out = (float*)d_out;                       // [B, N, H*F]
    float* att = out + (size_t)Bc * Nc * Hc * Fc;     // [B, H, N, N]

    float* ws = (float*)d_ws;
    float* fS = ws;                                   // [B,H,N,F]
    float* fN = fS + (size_t)Bc * Hc * Nc * Fc;       // [B,H,N,F]
    float* sS = fN + (size_t)Bc * Hc * Nc * Fc;       // [B,H,N]
    float* sN = sS + (size_t)Bc * Hc * Nc;            // [B,H,N]

    proj_kernel<<<Bc * Hc * (Nc / 64), 256, 0, stream>>>(
        X, Wself, Wneigh, aSelf, aNeigh, fS, fN, sS, sN);
    att_kernel<<<Bc * Nc, 256, 0, stream>>>(
        A, sS, sN, fS, fN, out, att);
}